// Round 5
// baseline (269.295 us; speedup 1.0000x reference)
//
#include <hip/hip_runtime.h>
#include <stdint.h>

// Gaussian kernel matrix K[i][j] = exp(-||x_i-x_j||^2/2), X: [16384][64] fp32.
// R5: maximize sustained outstanding stores (write-BW is outstanding-limited:
// fill kernel hits 6.6 TB/s at 11% occupancy via ~60 in-flight stores/wave).
//  - Pre-pass: X -> bf16 table Xb + premultiplied norm table in d_ws. Main
//    kernel loads MFMA-ready frags (no f32 staging regs, no cvt chain).
//  - 64x32 wave tiles (acc=32 VGPR), 8-wave blocks, ~150 VGPR -> 3 waves/SIMD.
//  - Depth-3 B prefetch (3-slot rotation): vmcnt wait for tile t's loads only
//    forces stores(t-3) drained -> 3-iteration store-drain window.
// Falls back to the proven R4 kernel if ws_size is too small.

typedef __attribute__((ext_vector_type(8))) short  s16x8;  // 8 bf16 (MFMA A/B frag)
typedef __attribute__((ext_vector_type(4))) float  f32x4;
typedef __attribute__((ext_vector_type(4))) unsigned short u16x4;

#define DDIM 64
#define JT 8
#define LOG2E      1.4426950408889634f   // 2c
#define HALF_LOG2E 0.7213475204444817f   // c ; K = exp2(-c||i||^2 - c||j||^2 + 2c dot)

// fp32 -> bf16 RNE on the bit pattern.
__device__ inline unsigned short bf16_rne(float x) {
  uint32_t u = __builtin_bit_cast(uint32_t, x);
  uint32_t r = (u + 0x7fffu + ((u >> 16) & 1u));
  return (unsigned short)(r >> 16);
}
__device__ inline float bf16_to_f32(unsigned short h) {
  return __builtin_bit_cast(float, (uint32_t)h << 16);
}

// ---- pre-pass 1: X (f32) -> Xb (bf16), flat coalesced ----
__global__ __launch_bounds__(256) void k_cvt(const float* __restrict__ X,
                                             unsigned short* __restrict__ Xb) {
  int g = blockIdx.x * 256 + threadIdx.x;      // one f32x4 per thread
  f32x4 v = reinterpret_cast<const f32x4*>(X)[g];
  u16x4 h;
  h[0] = bf16_rne(v[0]); h[1] = bf16_rne(v[1]);
  h[2] = bf16_rne(v[2]); h[3] = bf16_rne(v[3]);
  reinterpret_cast<u16x4*>(Xb)[g] = h;
}

// ---- pre-pass 2: per-row premultiplied norms from the bf16 table ----
__global__ __launch_bounds__(256) void k_norm(const unsigned short* __restrict__ Xb,
                                              float* __restrict__ nrm) {
  int row = blockIdx.x * 256 + threadIdx.x;    // one row per thread
  const s16x8* p = reinterpret_cast<const s16x8*>(Xb + (size_t)row * DDIM);
  float s = 0.f;
#pragma unroll
  for (int k = 0; k < 8; ++k) {
    s16x8 h = p[k];
#pragma unroll
    for (int e = 0; e < 8; ++e) {
      float f = bf16_to_f32((unsigned short)h[e]);
      s += f * f;
    }
  }
  nrm[row] = -HALF_LOG2E * s;
}

// ---- main kernel: 128x(128*JT) strip per block, 8 waves of 64x32 ----
__global__ __launch_bounds__(512, 3) void gauss_main(
    const unsigned short* __restrict__ Xb, const float* __restrict__ nrm,
    float* __restrict__ K, int n) {
  const int lane = threadIdx.x & 63;
  const int wid  = threadIdx.x >> 6;   // 8 waves: 2 (rows) x 4 (cols)
  const int wr = wid >> 2;             // 0..1
  const int wc = wid & 3;              // 0..3
  const int l15 = lane & 15;
  const int lq  = lane >> 4;           // 0..3

  const int i0    = blockIdx.x * 128 + wr * 64;   // output row base (this wave)
  const int jbase = blockIdx.y * (128 * JT);      // column strip base
  const int jw    = wc * 32;                       // wave col offset in tile

  // ---- A fragments (bf16, MFMA-ready) + row norms ----
  s16x8 a[4][2];
  float hA[4];
#pragma unroll
  for (int mi = 0; mi < 4; ++mi) {
    const int row = i0 + mi * 16 + l15;
#pragma unroll
    for (int ks = 0; ks < 2; ++ks)
      a[mi][ks] = *reinterpret_cast<const s16x8*>(
          Xb + (size_t)row * DDIM + ks * 32 + lq * 8);
    hA[mi] = nrm[row];
  }

  // ---- B: 3-slot register rotation (depth-3 prefetch) ----
  s16x8 b[3][2][2];
  float nb[3];
#define ISSUE_B(slot, jt_)                                                     \
  do {                                                                         \
    const int j0_ = jbase + (jt_) * 128 + jw;                                  \
    _Pragma("unroll") for (int ni = 0; ni < 2; ++ni) {                         \
      const int row_ = j0_ + ni * 16 + l15;                                    \
      _Pragma("unroll") for (int ks = 0; ks < 2; ++ks)                         \
        b[slot][ni][ks] = *reinterpret_cast<const s16x8*>(                     \
            Xb + (size_t)row_ * DDIM + ks * 32 + lq * 8);                      \
    }                                                                          \
    nb[slot] = nrm[j0_ + (lane & 31)];                                         \
  } while (0)

  ISSUE_B(0, 0);
  ISSUE_B(1, 1);
  ISSUE_B(2, 2);

#pragma unroll
  for (int jt = 0; jt < JT; ++jt) {
    const int slot = jt % 3;
    const int j0 = jbase + jt * 128 + jw;

    // col norms for this tile (waits only on slot's loads; stores from
    // iterations t-1, t-2 stay in flight in the vmcnt FIFO)
    float hcol[2][4];
#pragma unroll
    for (int ni = 0; ni < 2; ++ni)
#pragma unroll
      for (int r = 0; r < 4; ++r)
        hcol[ni][r] = __shfl(nb[slot], ni * 16 + lq * 4 + r);

    // MFMA, swapped operands: lane's 4 acc regs = 4 consecutive output cols
    f32x4 acc[4][2] = {};
#pragma unroll
    for (int ks = 0; ks < 2; ++ks)
#pragma unroll
      for (int mi = 0; mi < 4; ++mi)
#pragma unroll
        for (int ni = 0; ni < 2; ++ni)
          acc[mi][ni] = __builtin_amdgcn_mfma_f32_16x16x32_bf16(
              b[slot][ni][ks], a[mi][ks], acc[mi][ni], 0, 0, 0);

    // prefetch tile jt+3 into this slot (after MFMA consumed it, before stores)
    if (jt + 3 < JT) ISSUE_B(slot, jt + 3);
    // Pin VMEM order only (loads above stay above the stores below);
    // VALU/SALU/MFMA may cross freely.
    __builtin_amdgcn_sched_barrier(0x1 | 0x2 | 0x4 | 0x8);

    // epilogue: arg = hA + hcol + 2c*dot (<=0); K = exp2(arg)
#pragma unroll
    for (int mi = 0; mi < 4; ++mi) {
      const int rg = i0 + mi * 16 + l15;
      float* rowp = K + (size_t)rg * n;
#pragma unroll
      for (int ni = 0; ni < 2; ++ni) {
        const int c0 = j0 + ni * 16 + lq * 4;
        f32x4 v;
#pragma unroll
        for (int r = 0; r < 4; ++r) {
          float arg = fminf(hA[mi] + hcol[ni][r] + LOG2E * acc[mi][ni][r], 0.0f);
          float e = exp2f(arg);
          v[r] = (rg == c0 + r) ? 1.0f : e;   // exact diagonal
        }
        *reinterpret_cast<f32x4*>(rowp + c0) = v;
      }
    }
  }
#undef ISSUE_B
}

// ================= R4 fallback (used only if ws_size too small) =============
__device__ inline short cvt1(float x, float& sq) {
  uint32_t u = __builtin_bit_cast(uint32_t, x);
  uint32_t r = (u + 0x7fffu + ((u >> 16) & 1u)) & 0xffff0000u;
  float hf = __builtin_bit_cast(float, r);
  sq += hf * hf;
  return (short)(r >> 16);
}
__device__ inline void issue_row(const float* __restrict__ X, int row, int lq,
                                 f32x4 r[4]) {
  const f32x4* p = reinterpret_cast<const f32x4*>(X + (size_t)row * DDIM + lq * 8);
  const f32x4* q = reinterpret_cast<const f32x4*>(X + (size_t)row * DDIM + 32 + lq * 8);
  r[0] = p[0]; r[1] = p[1]; r[2] = q[0]; r[3] = q[1];
}
__device__ inline void cvt_row(const f32x4 r[4], s16x8 h[2], float& hnorm) {
  float s = 0.f;
#pragma unroll
  for (int ks = 0; ks < 2; ++ks) {
    s16x8 hh;
    hh[0] = cvt1(r[2*ks][0], s);   hh[1] = cvt1(r[2*ks][1], s);
    hh[2] = cvt1(r[2*ks][2], s);   hh[3] = cvt1(r[2*ks][3], s);
    hh[4] = cvt1(r[2*ks+1][0], s); hh[5] = cvt1(r[2*ks+1][1], s);
    hh[6] = cvt1(r[2*ks+1][2], s); hh[7] = cvt1(r[2*ks+1][3], s);
    h[ks] = hh;
  }
  s += __shfl_xor(s, 16);
  s += __shfl_xor(s, 32);
  hnorm = -HALF_LOG2E * s;
}
__global__ __launch_bounds__(256, 2) void gauss_gram_kernel(
    const float* __restrict__ X, float* __restrict__ K, int n) {
  const int lane = threadIdx.x & 63;
  const int wid  = threadIdx.x >> 6;
  const int wr = wid >> 1, wc = wid & 1;
  const int l15 = lane & 15, lq = lane >> 4;
  const int i0 = blockIdx.x * 128 + wr * 64;
  const int jstrip = blockIdx.y * (128 * JT);
  f32x4 araw[4][4];
#pragma unroll
  for (int mi = 0; mi < 4; ++mi) issue_row(X, i0 + mi * 16 + l15, lq, araw[mi]);
  f32x4 braw[4][4];
#pragma unroll
  for (int ni = 0; ni < 4; ++ni)
    issue_row(X, jstrip + wc * 64 + ni * 16 + l15, lq, braw[ni]);
  s16x8 a[4][2]; float hA[4];
#pragma unroll
  for (int mi = 0; mi < 4; ++mi) cvt_row(araw[mi], a[mi], hA[mi]);
#pragma unroll
  for (int jt = 0; jt < JT; ++jt) {
    const int j0 = jstrip + jt * 128 + wc * 64;
    s16x8 b[4][2]; float hcol[4][4];
#pragma unroll
    for (int ni = 0; ni < 4; ++ni) {
      float hB;
      cvt_row(braw[ni], b[ni], hB);
#pragma unroll
      for (int r = 0; r < 4; ++r) hcol[ni][r] = __shfl(hB, lq * 4 + r);
    }
    if (jt + 1 < JT) {
#pragma unroll
      for (int ni = 0; ni < 4; ++ni)
        issue_row(X, jstrip + (jt + 1) * 128 + wc * 64 + ni * 16 + l15, lq, braw[ni]);
    }
    __builtin_amdgcn_sched_barrier(0x1 | 0x2 | 0x4 | 0x8);
    f32x4 acc[4][4] = {};
#pragma unroll
    for (int ks = 0; ks < 2; ++ks)
#pragma unroll
      for (int mi = 0; mi < 4; ++mi)
#pragma unroll
        for (int ni = 0; ni < 4; ++ni)
          acc[mi][ni] = __builtin_amdgcn_mfma_f32_16x16x32_bf16(
              b[ni][ks], a[mi][ks], acc[mi][ni], 0, 0, 0);
#pragma unroll
    for (int mi = 0; mi < 4; ++mi) {
      const int rg = i0 + mi * 16 + l15;
      float* rowp = K + (size_t)rg * n;
#pragma unroll
      for (int ni = 0; ni < 4; ++ni) {
        const int c0 = j0 + ni * 16 + lq * 4;
        f32x4 v;
#pragma unroll
        for (int r = 0; r < 4; ++r) {
          float arg = fminf(hA[mi] + hcol[ni][r] + LOG2E * acc[mi][ni][r], 0.0f);
          float e = exp2f(arg);
          v[r] = (rg == c0 + r) ? 1.0f : e;
        }
        *reinterpret_cast<f32x4*>(rowp + c0) = v;
      }
    }
  }
}
// ============================================================================

extern "C" void kernel_launch(void* const* d_in, const int* in_sizes, int n_in,
                              void* d_out, int out_size, void* d_ws, size_t ws_size,
                              hipStream_t stream) {
  (void)n_in; (void)out_size;
  const float* X = (const float*)d_in[0];
  float* K = (float*)d_out;
  const int n = in_sizes[0] / DDIM;              // 16384
  const size_t need = (size_t)n * DDIM * 2 + (size_t)n * 4;  // Xb + nrm
  if (ws_size >= need) {
    unsigned short* Xb = (unsigned short*)d_ws;
    float* nrm = (float*)((char*)d_ws + (size_t)n * DDIM * 2);
    k_cvt<<<dim3(n * DDIM / 4 / 256), 256, 0, stream>>>(X, Xb);
    k_norm<<<dim3(n / 256), 256, 0, stream>>>(Xb, nrm);
    dim3 grid(n / 128, n / (128 * JT));          // (128, 16)
    gauss_main<<<grid, 512, 0, stream>>>(Xb, nrm, K, n);
  } else {
    dim3 grid(n / 128, n / (128 * JT));
    gauss_gram_kernel<<<grid, 256, 0, stream>>>(X, K, n);
  }
}

// Round 6
// 223.874 us; speedup vs baseline: 1.2029x; 1.2029x over previous
//
#include <hip/hip_runtime.h>
#include <stdint.h>

// Gaussian kernel matrix K[i][j] = exp(-||x_i-x_j||^2/2), X: [16384][64] fp32.
// R6 = R4 (proven 252.7 us) + LDS-transpose epilogue for fill-shaped stores:
// each global_store_dwordx4 now writes 8 rows x 128B FULL cache lines
// (fill-kernel shape) instead of 16 rows x 64B half-line segments. Per-wave
// private LDS buffer (wave-synchronous, no barriers), 36-float row stride for
// 16B alignment + near-uniform banking. Store->load vmcnt decoupling (B
// prefetch issued before stores, VMEM-only sched_barrier) kept from R4.

typedef __attribute__((ext_vector_type(8))) short s16x8;   // 8 bf16 (MFMA A/B frag)
typedef __attribute__((ext_vector_type(4))) float f32x4;

#define DDIM 64
#define JT 8
#define LROW 36   // LDS row stride in floats: 32 data + 4 pad (144 B, 16B-aligned)
#define LOG2E      1.4426950408889634f   // 2c
#define HALF_LOG2E 0.7213475204444817f   // c ; K = exp2(-c||i||^2 - c||j||^2 + 2c dot)

// fp32 -> bf16 RNE on the bit pattern; accumulates rounded value^2 for norms.
__device__ inline short cvt1(float x, float& sq) {
  uint32_t u = __builtin_bit_cast(uint32_t, x);
  uint32_t r = (u + 0x7fffu + ((u >> 16) & 1u)) & 0xffff0000u;
  float hf = __builtin_bit_cast(float, r);
  sq += hf * hf;
  return (short)(r >> 16);
}

// Issue the 4 dwordx4 loads for one fragment row. Raw loads only.
__device__ inline void issue_row(const float* __restrict__ X, int row, int lq,
                                 f32x4 r[4]) {
  const f32x4* p = reinterpret_cast<const f32x4*>(X + (size_t)row * DDIM + lq * 8);
  const f32x4* q = reinterpret_cast<const f32x4*>(X + (size_t)row * DDIM + 32 + lq * 8);
  r[0] = p[0]; r[1] = p[1]; r[2] = q[0]; r[3] = q[1];
}

// Raw f32 row data -> bf16 MFMA fragments + premultiplied norm (-c*||x||^2).
__device__ inline void cvt_row(const f32x4 r[4], s16x8 h[2], float& hnorm) {
  float s = 0.f;
#pragma unroll
  for (int ks = 0; ks < 2; ++ks) {
    s16x8 hh;
    hh[0] = cvt1(r[2*ks][0], s);   hh[1] = cvt1(r[2*ks][1], s);
    hh[2] = cvt1(r[2*ks][2], s);   hh[3] = cvt1(r[2*ks][3], s);
    hh[4] = cvt1(r[2*ks+1][0], s); hh[5] = cvt1(r[2*ks+1][1], s);
    hh[6] = cvt1(r[2*ks+1][2], s); hh[7] = cvt1(r[2*ks+1][3], s);
    h[ks] = hh;
  }
  s += __shfl_xor(s, 16);
  s += __shfl_xor(s, 32);
  hnorm = -HALF_LOG2E * s;
}

__global__ __launch_bounds__(256, 2) void gauss_gram_kernel(
    const float* __restrict__ X, float* __restrict__ K, int n) {
  const int lane = threadIdx.x & 63;
  const int wid  = threadIdx.x >> 6;   // 4 waves: 2x2 over the 128x128 tile
  const int wr = wid >> 1;
  const int wc = wid & 1;
  const int l15 = lane & 15;
  const int lq  = lane >> 4;           // 0..3
  const int r8  = lane >> 3;           // 0..7  (transpose-read row within group)
  const int e8  = lane & 7;            // 0..7  (transpose-read col chunk)

  // Per-wave private transpose buffer: 64 rows x LROW floats (wave-synchronous).
  __shared__ float tbuf[4][64 * LROW];
  float* buf = tbuf[wid];

  const int i0     = blockIdx.x * 128 + wr * 64;   // output row base (this wave)
  const int jstrip = blockIdx.y * (128 * JT);      // column strip base

  // ---- prologue: issue A loads, then B(jt=0) loads; cvt A while B flies ----
  f32x4 araw[4][4];
#pragma unroll
  for (int mi = 0; mi < 4; ++mi)
    issue_row(X, i0 + mi * 16 + l15, lq, araw[mi]);

  f32x4 braw[4][4];
#pragma unroll
  for (int ni = 0; ni < 4; ++ni)
    issue_row(X, jstrip + wc * 64 + ni * 16 + l15, lq, braw[ni]);

  s16x8 a[4][2]; float hA[4];
#pragma unroll
  for (int mi = 0; mi < 4; ++mi)
    cvt_row(araw[mi], a[mi], hA[mi]);
  // hA[mi] at lane l is -c*||row (i0+mi*16+l15)||^2 == this lane's output row.

#pragma unroll
  for (int jt = 0; jt < JT; ++jt) {
    const int j0 = jstrip + jt * 128 + wc * 64;

    // ---- cvt current B (waits only on braw loads, older than any stores) ----
    s16x8 b[4][2]; float hcol[4][4];
#pragma unroll
    for (int ni = 0; ni < 4; ++ni) {
      float hB;
      cvt_row(braw[ni], b[ni], hB);
#pragma unroll
      for (int r = 0; r < 4; ++r)
        hcol[ni][r] = __shfl(hB, lq * 4 + r);   // -c*norm of col j0+ni*16+lq*4+r
    }

    // ---- prefetch next tile's B (issued ahead of this tile's stores) ----
    if (jt + 1 < JT) {
#pragma unroll
      for (int ni = 0; ni < 4; ++ni)
        issue_row(X, jstrip + (jt + 1) * 128 + wc * 64 + ni * 16 + l15, lq, braw[ni]);
    }
    // Pin VMEM order only: prefetch loads stay above the stores below.
    __builtin_amdgcn_sched_barrier(0x1 | 0x2 | 0x4 | 0x8);

    // ---- MFMA, swapped operands: lane's 4 acc regs = 4 consecutive cols ----
    f32x4 acc[4][4] = {};
#pragma unroll
    for (int ks = 0; ks < 2; ++ks)
#pragma unroll
      for (int mi = 0; mi < 4; ++mi)
#pragma unroll
        for (int ni = 0; ni < 4; ++ni)
          acc[mi][ni] = __builtin_amdgcn_mfma_f32_16x16x32_bf16(
              b[ni][ks], a[mi][ks], acc[mi][ni], 0, 0, 0);

    // ---- epilogue in two 32-col halves: exp -> LDS transpose -> full-line stores ----
#pragma unroll
    for (int half = 0; half < 2; ++half) {
      // exp + ds_write: lane (l15 row, lq*4 col chunk) -> buf[row][colchunk]
#pragma unroll
      for (int mi = 0; mi < 4; ++mi) {
        const int rg = i0 + mi * 16 + l15;
#pragma unroll
        for (int nh = 0; nh < 2; ++nh) {
          const int ni = half * 2 + nh;
          const int c0 = j0 + ni * 16 + lq * 4;
          f32x4 v;
#pragma unroll
          for (int r = 0; r < 4; ++r) {
            float arg = fminf(hA[mi] + hcol[ni][r] + LOG2E * acc[mi][ni][r], 0.0f);
            float e = exp2f(arg);
            v[r] = (rg == c0 + r) ? 1.0f : e;   // exact diagonal
          }
          *reinterpret_cast<f32x4*>(
              buf + (mi * 16 + l15) * LROW + nh * 16 + lq * 4) = v;
        }
      }
      // ds_read (8 rows x 32 consecutive floats per instr) -> full-line stores
#pragma unroll
      for (int g = 0; g < 8; ++g) {
        f32x4 t = *reinterpret_cast<const f32x4*>(
            buf + (g * 8 + r8) * LROW + e8 * 4);
        const int rg = i0 + g * 8 + r8;
        *reinterpret_cast<f32x4*>(
            K + (size_t)rg * n + j0 + half * 32 + e8 * 4) = t;
      }
    }
  }
}

extern "C" void kernel_launch(void* const* d_in, const int* in_sizes, int n_in,
                              void* d_out, int out_size, void* d_ws, size_t ws_size,
                              hipStream_t stream) {
  (void)n_in; (void)d_ws; (void)ws_size; (void)out_size;
  const float* X = (const float*)d_in[0];
  float* K = (float*)d_out;
  const int n = in_sizes[0] / DDIM;          // 16384
  dim3 grid(n / 128, n / (128 * JT));        // (128, 16)
  gauss_gram_kernel<<<grid, 256, 0, stream>>>(X, K, n);
}